// Round 13
// baseline (24.987 us; speedup 1.0000x reference)
//
#include <hip/hip_runtime.h>
#include <hip/hip_bf16.h>
#include <math.h>

#define Tt 50
#define Dd 64
#define Bb 4096
#define Ss 64
#define ROWP 68  // padded LDS row (ushorts); 136 B rows, 8B-aligned

// DPP lane permute within 16-lane row (VALU, no DS pipe); ctrl is a template literal
template <int CTRL>
__device__ __forceinline__ float dppperm(float x) {
  return __builtin_bit_cast(
      float, __builtin_amdgcn_update_dpp(0, __builtin_bit_cast(int, x), CTRL,
                                         0xF, 0xF, true));
}
#define DPP_XOR1 0xB1    // quad_perm [1,0,3,2]
#define DPP_XOR2 0x4E    // quad_perm [2,3,0,1]
#define DPP_XOR7 0x141   // ROW_HALF_MIRROR (lane ^ 7 within 8)
#define DPP_XOR15 0x140  // ROW_MIRROR (lane ^ 15 within 16)

// 8-lane sum: xor-span {1,2,7} generates the full 8-group
__device__ __forceinline__ float gsum8(float v) {
  v += dppperm<DPP_XOR1>(v);
  v += dppperm<DPP_XOR2>(v);
  v += dppperm<DPP_XOR7>(v);
  return v;
}
// 16-lane sum
__device__ __forceinline__ float gsum16(float v) {
  v += dppperm<DPP_XOR1>(v);
  v += dppperm<DPP_XOR2>(v);
  v += dppperm<DPP_XOR7>(v);
  v += dppperm<DPP_XOR15>(v);
  return v;
}
__device__ __forceinline__ float wsum(float v) {  // 64-lane sum
  v = gsum16(v);
  v += __shfl_xor(v, 16, 64);
  v += __shfl_xor(v, 32, 64);
  return v;
}
__device__ __forceinline__ float wmax(float v) {  // 64-lane max
  v = fmaxf(v, dppperm<DPP_XOR1>(v));
  v = fmaxf(v, dppperm<DPP_XOR2>(v));
  v = fmaxf(v, dppperm<DPP_XOR7>(v));
  v = fmaxf(v, dppperm<DPP_XOR15>(v));
  v = fmaxf(v, __shfl_xor(v, 16, 64));
  v = fmaxf(v, __shfl_xor(v, 32, 64));
  return v;
}
__device__ __forceinline__ float bf2f(unsigned short u) {
  return __uint_as_float(((unsigned)u) << 16);
}
__device__ __forceinline__ unsigned short f2bf(float f) {
  __hip_bfloat16 h = __float2bfloat16(f);  // RNE
  return __builtin_bit_cast(unsigned short, h);
}
// log(q), cancellation-free: log(id+2)-log(id+1) == log1p(1/(id+1))
__device__ __forceinline__ float logq_f(int id) {
  float idf = (float)id;
  float r = log1pf(1.0f / (idf + 1.0f));
  return __logf(r * (1.0f / 12.2060776f));  // ln(200001)
}
__device__ __forceinline__ float fast_tanh(float x) {
  float ex = __expf(2.0f * x);
  return 1.0f - 2.0f * __builtin_amdgcn_rcpf(ex + 1.0f);
}

// 512-thread blocks: 8 waves, wave pair (j, half) handles b = blockIdx*4+j,
// dims [half*32, half*32+32). Lane = sub8 (t-subchunk) * 8 + dg8 (4-dim group).
__global__ __launch_bounds__(512, 4) void u2i_main(
    const float* __restrict__ item_table,
    const float* __restrict__ pos_table,
    const float* __restrict__ att_W,
    const float* __restrict__ att_b,
    const float* __restrict__ prelu_alpha,
    const float* __restrict__ zero_bias,
    const int* __restrict__ items_id,
    const int* __restrict__ position_id,
    const int* __restrict__ target_id,
    const int* __restrict__ keys_length,
    const int* __restrict__ sampled_ids,
    float* __restrict__ out_vec,   // [B]
    float* __restrict__ loss_ws)   // [gridDim] block partials
{
  __shared__ unsigned short sampB[Ss][ROWP];  // 8704 B
  __shared__ float score_lds[4][2][56];       // 1792 B
  __shared__ float ut1_lds[4][Dd];            // 1024 B
  __shared__ float part_lds[4][2][2];         // [j][half][op,tp]
  __shared__ float red[4];

  const int tid = threadIdx.x;
  const int lane = tid & 63;
  const int wave = tid >> 6;
  const int j = wave >> 1;     // local b index 0..3
  const int half = wave & 1;   // dim half
  const int b = (blockIdx.x << 2) | j;
  const int sub8 = lane >> 3;  // 0..7 (t subchunk)
  const int dg8 = lane & 7;    // 0..7 (dim group)
  const int d0 = half * 32 + (dg8 << 2);

  // ---- front-load ids + dependent chain ----
  int idreg = 0, pidreg = 0;
  if (lane < Tt) {
    idreg = items_id[b * Tt + lane];
    pidreg = position_id[b * Tt + lane];
  }
  const int kl = keys_length[b];
  const int tgt = target_id[b];
  const int sid = sampled_ids[lane];
  const int result = __shfl(idreg, kl - 1, 64);
  float4 tv4 = *(const float4*)&item_table[(size_t)tgt * Dd + d0];
  float4 tw4 = *(const float4*)&item_table[(size_t)result * Dd + d0];
  const float zb_r = zero_bias[result];
  const float zb_s = zero_bias[sid];

  // ---- sampB staging (block-cooperative; covered by barrier #1) ----
#pragma unroll
  for (int k = 0; k < 2; ++k) {
    int s = (tid >> 4) + 32 * k;
    int sd = (tid & 15) << 2;
    float4 x = *(const float4*)&item_table[(size_t)sampled_ids[s] * Dd + sd];
    ushort4 o;
    o.x = f2bf(x.x); o.y = f2bf(x.y); o.z = f2bf(x.z); o.w = f2bf(x.w);
    *(ushort4*)&sampB[s][sd] = o;
  }

  // ---- gathers: 7 per wave (this wave's 32-dim half of all 50 rows) ----
  const float4 Wi4 = *(const float4*)&att_W[d0];
  const float4 Wp4 = *(const float4*)&att_W[Dd + d0];
  unsigned pk0[7], pk1[7];
  float v[7];
#pragma unroll
  for (int c = 0; c < 7; ++c) {
    const int t = 8 * c + sub8;
    const int tt = (t < Tt) ? t : 0;  // dummy for t=50..55, masked later
    int iid = __shfl(idreg, tt, 64);
    int pid = __shfl(pidreg, tt, 64);
    float4 x = *(const float4*)&item_table[(size_t)iid * Dd + d0];
    float4 p = *(const float4*)&pos_table[pid * Dd + d0];
    v[c] = x.x * Wi4.x + x.y * Wi4.y + x.z * Wi4.z + x.w * Wi4.w +
           p.x * Wp4.x + p.y * Wp4.y + p.z * Wp4.z + p.w * Wp4.w;
    pk0[c] = ((unsigned)f2bf(x.y) << 16) | f2bf(x.x);
    pk1[c] = ((unsigned)f2bf(x.w) << 16) | f2bf(x.z);
  }
  // 8-lane butterfly over dg8 -> half-dot for t, replicated in 8-lane group
#pragma unroll
  for (int c = 0; c < 7; ++c) v[c] = gsum8(v[c]);
  if (dg8 == 0) {
#pragma unroll
    for (int c = 0; c < 7; ++c) score_lds[j][half][8 * c + sub8] = v[c];
  }
  __syncthreads();  // #1: score halves + sampB visible

  // combine halves; softmax (computed redundantly by both waves, identical)
  const float ab = att_b[0];
  float lmax = -INFINITY;
#pragma unroll
  for (int c = 0; c < 7; ++c) {
    const int t = 8 * c + sub8;
    v[c] = fast_tanh(v[c] + score_lds[j][half ^ 1][t] + ab);
    if (t < kl) lmax = fmaxf(lmax, v[c]);
  }
  lmax = fmaxf(lmax, __shfl_xor(lmax, 8, 64));
  lmax = fmaxf(lmax, __shfl_xor(lmax, 16, 64));
  lmax = fmaxf(lmax, __shfl_xor(lmax, 32, 64));
  float lsum = 0.0f;
#pragma unroll
  for (int c = 0; c < 7; ++c) {
    const int t = 8 * c + sub8;
    float e = (t < kl) ? __expf(v[c] - lmax) : 0.0f;
    v[c] = e;
    lsum += e;
  }
  lsum += __shfl_xor(lsum, 8, 64);
  lsum += __shfl_xor(lsum, 16, 64);
  lsum += __shfl_xor(lsum, 32, 64);
  const float inv = __builtin_amdgcn_rcpf(lsum);
  const unsigned long long mask = __ballot(lane < Tt - 1 && idreg != 0);

  // ---- pooling partials over t = 8c+sub8 (4 dims per lane) ----
  float4 sp4 = make_float4(0, 0, 0, 0), u14 = make_float4(0, 0, 0, 0);
#pragma unroll
  for (int c = 0; c < 7; ++c) {
    const int t = 8 * c + sub8;
    float wt = v[c] * inv;
    float wm = ((mask >> t) & 1ull) ? wt : 0.0f;
    float x0 = bf2f((unsigned short)pk0[c]);
    float x1 = bf2f((unsigned short)(pk0[c] >> 16));
    float x2 = bf2f((unsigned short)pk1[c]);
    float x3 = bf2f((unsigned short)(pk1[c] >> 16));
    sp4.x += wt * x0; sp4.y += wt * x1; sp4.z += wt * x2; sp4.w += wt * x3;
    u14.x += wm * x0; u14.y += wm * x1; u14.z += wm * x2; u14.w += wm * x3;
  }
#pragma unroll
  for (int mm = 8; mm <= 32; mm <<= 1) {
    sp4.x += __shfl_xor(sp4.x, mm, 64); sp4.y += __shfl_xor(sp4.y, mm, 64);
    sp4.z += __shfl_xor(sp4.z, mm, 64); sp4.w += __shfl_xor(sp4.w, mm, 64);
    u14.x += __shfl_xor(u14.x, mm, 64); u14.y += __shfl_xor(u14.y, mm, 64);
    u14.z += __shfl_xor(u14.z, mm, 64); u14.w += __shfl_xor(u14.w, mm, 64);
  }

  float4 al = *(const float4*)&prelu_alpha[d0];
  float4 sp;
  sp.x = sp4.x > 0.0f ? sp4.x : al.x * sp4.x;
  sp.y = sp4.y > 0.0f ? sp4.y : al.y * sp4.y;
  sp.z = sp4.z > 0.0f ? sp4.z : al.z * sp4.z;
  sp.w = sp4.w > 0.0f ? sp4.w : al.w * sp4.w;
  float op = sp.x * tv4.x + sp.y * tv4.y + sp.z * tv4.z + sp.w * tv4.w;
  float tp = u14.x * tw4.x + u14.y * tw4.y + u14.z * tw4.z + u14.w * tw4.w;
  op = gsum8(op);  // sum over dg8 -> this wave's 32-dim half
  tp = gsum8(tp);
  if (lane == 0) {
    part_lds[j][half][0] = op;
    part_lds[j][half][1] = tp;
  }
  if (sub8 == 0) *(float4*)&ut1_lds[j][d0] = u14;  // both halves fill [64]
  __syncthreads();  // #2: parts + ut1 visible

  if (half == 0) {
    if (lane == 0) out_vec[b] = part_lds[j][0][0] + part_lds[j][1][0];
    float tl = part_lds[j][0][1] + part_lds[j][1][1] + zb_r - logq_f(result);

    // ---- phase 4 (half-0 wave only): lane = s -> sampled logits + loss ----
    const ushort4* srow = (const ushort4*)&sampB[lane][0];
    const float4* up = (const float4*)&ut1_lds[j][0];
    float acc = 0.0f;
#pragma unroll
    for (int q = 0; q < 16; ++q) {
      ushort4 u = srow[q];
      float4 uv = up[q];  // uniform -> broadcast
      acc += bf2f(u.x) * uv.x + bf2f(u.y) * uv.y + bf2f(u.z) * uv.z +
             bf2f(u.w) * uv.w;
    }
    float sl = acc + zb_s - logq_f(sid);
    if (sid == result) sl -= 1e9f;
    float mx = fmaxf(tl, wmax(sl));
    float se = wsum(__expf(sl - mx)) + __expf(tl - mx);
    float loss_b = (mx + __logf(se)) - tl;
    if (lane == 0) red[j] = loss_b;
  }
  __syncthreads();  // #3
  if (tid == 0) loss_ws[blockIdx.x] = (red[0] + red[1]) + (red[2] + red[3]);
}

__global__ __launch_bounds__(256) void loss_reduce_kernel(
    const float* __restrict__ ws, float* __restrict__ out_loss) {
  __shared__ float red[4];
  const int tid = threadIdx.x;
  float acc = ws[tid] + ws[tid + 256] + ws[tid + 512] + ws[tid + 768];
  acc = wsum(acc);
  if ((tid & 63) == 0) red[tid >> 6] = acc;
  __syncthreads();
  if (tid == 0)
    out_loss[0] = ((red[0] + red[1]) + (red[2] + red[3])) * (1.0f / (float)Bb);
}

extern "C" void kernel_launch(void* const* d_in, const int* in_sizes, int n_in,
                              void* d_out, int out_size, void* d_ws, size_t ws_size,
                              hipStream_t stream) {
  const float* item_table  = (const float*)d_in[0];
  const float* pos_table   = (const float*)d_in[1];
  const float* att_W       = (const float*)d_in[2];
  const float* att_b       = (const float*)d_in[3];
  const float* prelu_alpha = (const float*)d_in[4];
  const float* zero_bias   = (const float*)d_in[5];
  const int* items_id      = (const int*)d_in[6];
  const int* position_id   = (const int*)d_in[7];
  const int* target_id     = (const int*)d_in[8];
  const int* keys_length   = (const int*)d_in[9];
  const int* sampled_ids   = (const int*)d_in[10];

  float* out = (float*)d_out;     // [0..4095]=output, [4096]=loss
  float* loss_ws = (float*)d_ws;  // gridDim floats (block partials)

  u2i_main<<<Bb / 4, 512, 0, stream>>>(
      item_table, pos_table, att_W, att_b, prelu_alpha, zero_bias,
      items_id, position_id, target_id, keys_length, sampled_ids,
      out, loss_ws);
  loss_reduce_kernel<<<1, 256, 0, stream>>>(loss_ws, out + Bb);
}

// Round 14
// 20.271 us; speedup vs baseline: 1.2326x; 1.2326x over previous
//
#include <hip/hip_runtime.h>
#include <hip/hip_bf16.h>
#include <math.h>

#define Tt 50
#define Dd 64
#define Bb 4096
#define Ss 64
#define ROWP 68  // padded LDS row (ushorts); 136 B rows, 8B-aligned

// DPP lane permute within 16-lane row (VALU, no DS pipe); ctrl is a template literal
template <int CTRL>
__device__ __forceinline__ float dppperm(float x) {
  return __builtin_bit_cast(
      float, __builtin_amdgcn_update_dpp(0, __builtin_bit_cast(int, x), CTRL,
                                         0xF, 0xF, true));
}
#define DPP_XOR1 0xB1    // quad_perm [1,0,3,2]
#define DPP_XOR2 0x4E    // quad_perm [2,3,0,1]
#define DPP_XOR7 0x141   // ROW_HALF_MIRROR (lane ^ 7 within 8)
#define DPP_XOR15 0x140  // ROW_MIRROR (lane ^ 15 within 16)

// full 16-lane sum (xor-span {1,2,7,15} covers the 16-group), all lanes get total
__device__ __forceinline__ float gsum16(float v) {
  v += dppperm<DPP_XOR1>(v);
  v += dppperm<DPP_XOR2>(v);
  v += dppperm<DPP_XOR7>(v);
  v += dppperm<DPP_XOR15>(v);
  return v;
}
__device__ __forceinline__ float wsum(float v) {  // 64-lane sum
  v = gsum16(v);
  v += __shfl_xor(v, 16, 64);
  v += __shfl_xor(v, 32, 64);
  return v;
}
__device__ __forceinline__ float wmax(float v) {  // 64-lane max
  v = fmaxf(v, dppperm<DPP_XOR1>(v));
  v = fmaxf(v, dppperm<DPP_XOR2>(v));
  v = fmaxf(v, dppperm<DPP_XOR7>(v));
  v = fmaxf(v, dppperm<DPP_XOR15>(v));
  v = fmaxf(v, __shfl_xor(v, 16, 64));
  v = fmaxf(v, __shfl_xor(v, 32, 64));
  return v;
}
__device__ __forceinline__ float bf2f(unsigned short u) {
  return __uint_as_float(((unsigned)u) << 16);
}
__device__ __forceinline__ unsigned short f2bf(float f) {
  __hip_bfloat16 h = __float2bfloat16(f);  // RNE
  return __builtin_bit_cast(unsigned short, h);
}
// log(q), cancellation-free: log(id+2)-log(id+1) == log1p(1/(id+1))
__device__ __forceinline__ float logq_f(int id) {
  float idf = (float)id;
  float r = log1pf(1.0f / (idf + 1.0f));
  return __logf(r * (1.0f / 12.2060776f));  // ln(200001)
}
__device__ __forceinline__ float fast_tanh(float x) {
  float ex = __expf(2.0f * x);
  return 1.0f - 2.0f * __builtin_amdgcn_rcpf(ex + 1.0f);
}

__global__ __launch_bounds__(256, 4) void u2i_main(
    const float* __restrict__ item_table,
    const float* __restrict__ pos_table,
    const float* __restrict__ att_W,
    const float* __restrict__ att_b,
    const float* __restrict__ prelu_alpha,
    const float* __restrict__ zero_bias,
    const int* __restrict__ items_id,
    const int* __restrict__ position_id,
    const int* __restrict__ target_id,
    const int* __restrict__ keys_length,
    const int* __restrict__ sampled_ids,
    float* __restrict__ out_vec,   // [B]
    float* __restrict__ loss_ws)   // [gridDim] block partials
{
  __shared__ unsigned short sampB[Ss][ROWP];  // 8704 B (block-shared, bf16)
  __shared__ float ut1_lds[4][Dd];            // 1024 B (wave-private rows)
  __shared__ float red[4];

  const int tid = threadIdx.x;
  const int lane = tid & 63;
  const int w = tid >> 6;
  const int b = (blockIdx.x << 2) | w;
  const int sub = lane >> 4;  // 0..3
  const int dg = lane & 15;   // 0..15
  const int d0g = dg << 2;

  // ---- front-load the whole dependent chain BEFORE the barrier ----
  int idreg = 0, pidreg = 0;
  if (lane < Tt) {
    idreg = items_id[b * Tt + lane];
    pidreg = position_id[b * Tt + lane];
  }
  const int kl = keys_length[b];
  const int tgt = target_id[b];
  const int sid = sampled_ids[lane];
  const int result = __shfl(idreg, kl - 1, 64);
  float4 tv4 = *(const float4*)&item_table[(size_t)tgt * Dd + d0g];
  float4 tw4 = *(const float4*)&item_table[(size_t)result * Dd + d0g];
  const float zb_r = zero_bias[result];
  const float zb_s = zero_bias[sid];

  // ---- block-cooperative sampled-table staging, then the ONLY barrier ----
#pragma unroll
  for (int k = 0; k < 4; ++k) {
    int s = (tid >> 4) + 16 * k;
    float4 x = *(const float4*)&item_table[(size_t)sampled_ids[s] * Dd + ((tid & 15) << 2)];
    ushort4 o;
    o.x = f2bf(x.x); o.y = f2bf(x.y); o.z = f2bf(x.z); o.w = f2bf(x.w);
    *(ushort4*)&sampB[s][(tid & 15) << 2] = o;
  }
  __syncthreads();

  // ---- fused gather + score partial; items stay in registers (packed bf16) ----
  const float4 Wi4 = *(const float4*)&att_W[d0g];
  const float4 Wp4 = *(const float4*)&att_W[Dd + d0g];
  unsigned pk0[13], pk1[13];
  float v[13];
#pragma unroll
  for (int c = 0; c < 13; ++c) {
    const int t = 4 * c + sub;
    const int tt = (t < Tt) ? t : 0;  // dummy row for t=50,51; masked later
    int iid = __shfl(idreg, tt, 64);   // ids from registers (DS pipe, VMEM freed)
    int pid = __shfl(pidreg, tt, 64);
    float4 x = *(const float4*)&item_table[(size_t)iid * Dd + d0g];
    float4 p = *(const float4*)&pos_table[pid * Dd + d0g];
    v[c] = x.x * Wi4.x + x.y * Wi4.y + x.z * Wi4.z + x.w * Wi4.w +
           p.x * Wp4.x + p.y * Wp4.y + p.z * Wp4.z + p.w * Wp4.w;
    pk0[c] = ((unsigned)f2bf(x.y) << 16) | f2bf(x.x);
    pk1[c] = ((unsigned)f2bf(x.w) << 16) | f2bf(x.z);
  }
  // 16-lane DPP butterflies: score of t=4c+sub lands in all lanes of group sub
#pragma unroll
  for (int c = 0; c < 13; ++c) v[c] = gsum16(v[c]);

  const float ab = att_b[0];
  float lmax = -INFINITY;
#pragma unroll
  for (int c = 0; c < 13; ++c) {
    const int t = 4 * c + sub;
    v[c] = fast_tanh(v[c] + ab);
    if (t < kl) lmax = fmaxf(lmax, v[c]);
  }
  lmax = fmaxf(lmax, __shfl_xor(lmax, 16, 64));
  lmax = fmaxf(lmax, __shfl_xor(lmax, 32, 64));
  float lsum = 0.0f;
#pragma unroll
  for (int c = 0; c < 13; ++c) {
    const int t = 4 * c + sub;
    float e = (t < kl) ? __expf(v[c] - lmax) : 0.0f;
    v[c] = e;
    lsum += e;
  }
  lsum += __shfl_xor(lsum, 16, 64);
  lsum += __shfl_xor(lsum, 32, 64);
  const float inv = __builtin_amdgcn_rcpf(lsum);
  const unsigned long long mask = __ballot(lane < Tt - 1 && idreg != 0);

  // ---- phase 3 from registers: pooling partials over t = 4c+sub ----
  float4 sp4 = make_float4(0, 0, 0, 0), u14 = make_float4(0, 0, 0, 0);
#pragma unroll
  for (int c = 0; c < 13; ++c) {
    const int t = 4 * c + sub;
    float wt = v[c] * inv;
    float wm = ((mask >> t) & 1ull) ? wt : 0.0f;
    float x0 = bf2f((unsigned short)pk0[c]);
    float x1 = bf2f((unsigned short)(pk0[c] >> 16));
    float x2 = bf2f((unsigned short)pk1[c]);
    float x3 = bf2f((unsigned short)(pk1[c] >> 16));
    sp4.x += wt * x0; sp4.y += wt * x1; sp4.z += wt * x2; sp4.w += wt * x3;
    u14.x += wm * x0; u14.y += wm * x1; u14.z += wm * x2; u14.w += wm * x3;
  }
#pragma unroll
  for (int mm = 16; mm <= 32; mm <<= 1) {
    sp4.x += __shfl_xor(sp4.x, mm, 64); sp4.y += __shfl_xor(sp4.y, mm, 64);
    sp4.z += __shfl_xor(sp4.z, mm, 64); sp4.w += __shfl_xor(sp4.w, mm, 64);
    u14.x += __shfl_xor(u14.x, mm, 64); u14.y += __shfl_xor(u14.y, mm, 64);
    u14.z += __shfl_xor(u14.z, mm, 64); u14.w += __shfl_xor(u14.w, mm, 64);
  }

  float4 al = *(const float4*)&prelu_alpha[d0g];
  float4 sp;
  sp.x = sp4.x > 0.0f ? sp4.x : al.x * sp4.x;
  sp.y = sp4.y > 0.0f ? sp4.y : al.y * sp4.y;
  sp.z = sp4.z > 0.0f ? sp4.z : al.z * sp4.z;
  sp.w = sp4.w > 0.0f ? sp4.w : al.w * sp4.w;
  float op = sp.x * tv4.x + sp.y * tv4.y + sp.z * tv4.z + sp.w * tv4.w;
  float tp = u14.x * tw4.x + u14.y * tw4.y + u14.z * tw4.z + u14.w * tw4.w;
  // 16-lane DPP reduce over dg covers all 64 dims
  op = gsum16(op);
  tp = gsum16(tp);
  if (lane == 0) out_vec[b] = op;
  float tl = tp + zb_r - logq_f(result);
  if (lane < 16) *(float4*)&ut1_lds[w][d0g] = u14;

  // ---- phase 4: lane = s -> sampled logits from LDS-staged bf16 table ----
  const ushort4* srow = (const ushort4*)&sampB[lane][0];
  const float4* up = (const float4*)&ut1_lds[w][0];
  float acc = 0.0f;
#pragma unroll
  for (int q = 0; q < 16; ++q) {
    ushort4 u = srow[q];
    float4 uv = up[q];  // uniform -> broadcast
    acc += bf2f(u.x) * uv.x + bf2f(u.y) * uv.y + bf2f(u.z) * uv.z +
           bf2f(u.w) * uv.w;
  }
  float sl = acc + zb_s - logq_f(sid);
  if (sid == result) sl -= 1e9f;
  float mx = fmaxf(tl, wmax(sl));
  float se = wsum(__expf(sl - mx)) + __expf(tl - mx);
  float loss_b = (mx + __logf(se)) - tl;
  if (lane == 0) red[w] = loss_b;
  __syncthreads();
  if (tid == 0) loss_ws[blockIdx.x] = (red[0] + red[1]) + (red[2] + red[3]);
}

__global__ __launch_bounds__(256) void loss_reduce_kernel(
    const float* __restrict__ ws, float* __restrict__ out_loss) {
  __shared__ float red[4];
  const int tid = threadIdx.x;
  float acc = ws[tid] + ws[tid + 256] + ws[tid + 512] + ws[tid + 768];
  acc = wsum(acc);
  if ((tid & 63) == 0) red[tid >> 6] = acc;
  __syncthreads();
  if (tid == 0)
    out_loss[0] = ((red[0] + red[1]) + (red[2] + red[3])) * (1.0f / (float)Bb);
}

extern "C" void kernel_launch(void* const* d_in, const int* in_sizes, int n_in,
                              void* d_out, int out_size, void* d_ws, size_t ws_size,
                              hipStream_t stream) {
  const float* item_table  = (const float*)d_in[0];
  const float* pos_table   = (const float*)d_in[1];
  const float* att_W       = (const float*)d_in[2];
  const float* att_b       = (const float*)d_in[3];
  const float* prelu_alpha = (const float*)d_in[4];
  const float* zero_bias   = (const float*)d_in[5];
  const int* items_id      = (const int*)d_in[6];
  const int* position_id   = (const int*)d_in[7];
  const int* target_id     = (const int*)d_in[8];
  const int* keys_length   = (const int*)d_in[9];
  const int* sampled_ids   = (const int*)d_in[10];

  float* out = (float*)d_out;     // [0..4095]=output, [4096]=loss
  float* loss_ws = (float*)d_ws;  // gridDim floats (block partials)

  u2i_main<<<Bb / 4, 256, 0, stream>>>(
      item_table, pos_table, att_W, att_b, prelu_alpha, zero_bias,
      items_id, position_id, target_id, keys_length, sampled_ids,
      out, loss_ws);
  loss_reduce_kernel<<<1, 256, 0, stream>>>(loss_ws, out + Bb);
}